// Round 7
// baseline (312.872 us; speedup 1.0000x reference)
//
#include <hip/hip_runtime.h>

#define N_NODES 20000
#define MP      20096   // N_NODES padded to multiple of 128
#define N_EDGES 320000
#define DIM     512
#define SCAN_BLOCKS 79    // ceil(20224/256)
#define FILL_BLOCKS 1250  // N_EDGES/256
#define CVT_BLOCKS  10048 // MP*DIM/4/256
#define W_BLOCKS    512   // 16x16 tiles x 2 weights
#define MAXP_BLOCKS 256
#define MAXP_ROWS   79    // ceil(20000/256)

typedef _Float16 half8 __attribute__((ext_vector_type(8)));
typedef _Float16 half4v __attribute__((ext_vector_type(4)));
typedef float floatx4 __attribute__((ext_vector_type(4)));

#define GLD16(g, l) __builtin_amdgcn_global_load_lds( \
    (const __attribute__((address_space(1))) unsigned int*)(g), \
    (__attribute__((address_space(3))) unsigned int*)(l), 16, 0, 0)

__global__ void k_count(const int* __restrict__ dst, int* __restrict__ cnt) {
    int e = blockIdx.x * blockDim.x + threadIdx.x;
    if (e < N_EDGES) atomicAdd(&cnt[dst[e]], 1);
}

// ---------------------------------------------------------------- parallel scan
__global__ __launch_bounds__(256) void k_scan_a(const int* __restrict__ cnt,
                                                int* __restrict__ bsum) {
    __shared__ int buf[256];
    int gi = blockIdx.x * 256 + threadIdx.x;
    buf[threadIdx.x] = (gi < N_NODES) ? cnt[gi] : 0;
    __syncthreads();
    for (int off = 128; off > 0; off >>= 1) {
        if (threadIdx.x < off) buf[threadIdx.x] += buf[threadIdx.x + off];
        __syncthreads();
    }
    if (threadIdx.x == 0) bsum[blockIdx.x] = buf[0];
}

__global__ __launch_bounds__(128) void k_scan_b(const int* __restrict__ bsum,
                                                int* __restrict__ bbase) {
    __shared__ int buf[128];
    int tid = threadIdx.x;
    int v = (tid < SCAN_BLOCKS) ? bsum[tid] : 0;
    buf[tid] = v;
    __syncthreads();
    for (int off = 1; off < 128; off <<= 1) {
        int t = (tid >= off) ? buf[tid - off] : 0;
        __syncthreads();
        buf[tid] += t;
        __syncthreads();
    }
    if (tid < SCAN_BLOCKS) bbase[tid] = buf[tid] - v;  // exclusive
}

__global__ __launch_bounds__(256) void k_scan_c(const int* __restrict__ cnt,
                                                const int* __restrict__ bbase,
                                                int* __restrict__ offs,
                                                int* __restrict__ cursor,
                                                float* __restrict__ dinv) {
    __shared__ int buf[256];
    int tid = threadIdx.x;
    int gi = blockIdx.x * 256 + tid;
    int v = (gi < N_NODES) ? cnt[gi] : 0;
    buf[tid] = v;
    __syncthreads();
    for (int off = 1; off < 256; off <<= 1) {
        int t = (tid >= off) ? buf[tid - off] : 0;
        __syncthreads();
        buf[tid] += t;
        __syncthreads();
    }
    int base = bbase[blockIdx.x];
    if (gi < N_NODES) {
        int incl = base + buf[tid];
        offs[gi + 1] = incl;
        cursor[gi] = incl - v;
        dinv[gi] = rsqrtf((float)v + 1.0f);  // +1 self-loop
        if (gi == 0) offs[0] = 0;
    } else if (gi < MP) {
        dinv[gi] = 0.f;  // pad rows: zero (poison-proofs GEMM epilogue)
    }
}

// ---------------------------------------------------------------- fused prep
// blocks [0,1250): CSR fill; [1250,11298): feature cvt; [11298,11810): W transpose
__global__ __launch_bounds__(256) void k_prep(const int* __restrict__ src,
                                              const int* __restrict__ dst,
                                              int* __restrict__ cursor,
                                              int* __restrict__ csr_src,
                                              const float* __restrict__ F,
                                              _Float16* __restrict__ A,
                                              const float* __restrict__ W1,
                                              const float* __restrict__ W2,
                                              _Float16* __restrict__ Wt1,
                                              _Float16* __restrict__ Wt2) {
    int b = blockIdx.x;
    if (b < FILL_BLOCKS) {
        int e = b * 256 + threadIdx.x;
        int d = dst[e];
        int pos = atomicAdd(&cursor[d], 1);
        csr_src[pos] = src[e];
        return;
    }
    if (b < FILL_BLOCKS + CVT_BLOCKS) {
        int i = (b - FILL_BLOCKS) * 256 + threadIdx.x;  // over MP*DIM/4
        int e = i * 4;
        int row = e >> 9;
        half4v o;
        if (row < N_NODES) {
            float4 v = *(const float4*)&F[e];
            o[0] = (_Float16)v.x; o[1] = (_Float16)v.y;
            o[2] = (_Float16)v.z; o[3] = (_Float16)v.w;
        } else {
            o[0] = o[1] = o[2] = o[3] = (_Float16)0.f;
        }
        *(half4v*)&A[e] = o;
        return;
    }
    // W transpose: fp32 [k][n] -> f16 [n][k]
    int local = b - (FILL_BLOCKS + CVT_BLOCKS);
    int z = local >> 8, t = local & 255;
    const float* W = z ? W2 : W1;
    _Float16* Wt = z ? Wt2 : Wt1;
    __shared__ float tile[32][33];
    int bx = (t & 15) * 32, by = (t >> 4) * 32;
    int x = threadIdx.x & 31, y4 = (threadIdx.x >> 5) * 4;
#pragma unroll
    for (int r = 0; r < 4; ++r)
        tile[y4 + r][x] = W[(size_t)(by + y4 + r) * DIM + bx + x];
    __syncthreads();
#pragma unroll
    for (int r = 0; r < 4; ++r)
        Wt[(size_t)(bx + y4 + r) * DIM + by + x] = (_Float16)tile[x][y4 + r];
}

// ---------------------------------------------------------------- MFMA GEMM
// g[MP,512] f16 = dinv[row] * (A[MP,512] f16 @ Bt[n][k] f16)
__global__ __launch_bounds__(256) void k_gemm_f16(const _Float16* __restrict__ A,
                                                  const _Float16* __restrict__ Bt,
                                                  const float* __restrict__ dinv,
                                                  _Float16* __restrict__ G) {
    __shared__ _Float16 As[128 * 32];  // [m][k], k contiguous
    __shared__ _Float16 Bs[128 * 32];  // [n][k], k contiguous

    int t = threadIdx.x;
    int w = t >> 6, lane = t & 63;
    int lm = lane & 15, quad = lane >> 4;
    int m0 = blockIdx.x * 128, n0 = blockIdx.y * 128;
    int wm = (w & 1) * 64, wn = (w >> 1) * 64;

    floatx4 acc[4][4];
#pragma unroll
    for (int i = 0; i < 4; ++i)
#pragma unroll
        for (int j = 0; j < 4; ++j) acc[i][j] = (floatx4){0.f, 0.f, 0.f, 0.f};

    for (int k0 = 0; k0 < DIM; k0 += 32) {
        __syncthreads();
#pragma unroll
        for (int i = 0; i < 2; ++i) {
            int s = i * 256 + t;
            int m = s >> 2, kk = (s & 3) * 8;
            GLD16(A + (size_t)(m0 + m) * DIM + k0 + kk, As + s * 8);
            GLD16(Bt + (size_t)(n0 + m) * DIM + k0 + kk, Bs + s * 8);
        }
        __syncthreads();

        half8 af[4], bf[4];
#pragma unroll
        for (int i = 0; i < 4; ++i)
            af[i] = *(const half8*)&As[(wm + i * 16 + lm) * 32 + quad * 8];
#pragma unroll
        for (int j = 0; j < 4; ++j)
            bf[j] = *(const half8*)&Bs[(wn + j * 16 + lm) * 32 + quad * 8];
#pragma unroll
        for (int i = 0; i < 4; ++i)
#pragma unroll
            for (int j = 0; j < 4; ++j)
                acc[i][j] = __builtin_amdgcn_mfma_f32_16x16x32_f16(af[i], bf[j], acc[i][j], 0, 0, 0);
    }

#pragma unroll
    for (int i = 0; i < 4; ++i)
#pragma unroll
        for (int r = 0; r < 4; ++r) {
            int row = m0 + wm + i * 16 + quad * 4 + r;
            float dd = dinv[row];  // 0 on pad rows
#pragma unroll
            for (int j = 0; j < 4; ++j) {
                int col = n0 + wn + j * 16 + lm;
                G[(size_t)row * DIM + col] = (_Float16)(dd * acc[i][j][r]);
            }
        }
}

// ---------------------------------------------------------------- aggregation
// Feature-chunked, XCD-affine gather:
//   chunk = blockIdx & 7  -> 64-feature slab (20096*64*2B = 2.57 MB < 4 MB L2/XCD);
//   blockIdx%8 rides the workgroup->XCD round-robin so each XCD's L2 holds one slab.
// Wave = (node, chunk). lane = (edge-slot 0..7) x (feature-group 0..7):
//   8 edges gathered per load; xor-shuffle reduce over slots; no LDS.
__global__ __launch_bounds__(256) void k_agg_x(const _Float16* __restrict__ g,
                                               const float* __restrict__ dinv,
                                               const int* __restrict__ offs,
                                               const int* __restrict__ csr_src,
                                               const float* __restrict__ bias,
                                               _Float16* __restrict__ out, int nodeCount) {
    int chunk = blockIdx.x & 7;
    int node = (blockIdx.x >> 3) * 4 + (threadIdx.x >> 6);
    int lane = threadIdx.x & 63;
    int slot = lane >> 3, fg = lane & 7;
    int fbase = chunk * 64 + fg * 8;  // this lane's half8 feature offset

    if (node >= N_NODES) {  // pad row (only when nodeCount==MP): zero this chunk
        if (node < nodeCount && slot == 0) {
            half8 z;
#pragma unroll
            for (int i = 0; i < 8; ++i) z[i] = (_Float16)0.f;
            *(half8*)&out[(size_t)node * DIM + fbase] = z;
        }
        return;
    }

    float acc[8];
    if (slot == 0) {  // self term handled by slot 0 only
        half8 self = *(const half8*)&g[(size_t)node * DIM + fbase];
#pragma unroll
        for (int i = 0; i < 8; ++i) acc[i] = (float)self[i];
    } else {
#pragma unroll
        for (int i = 0; i < 8; ++i) acc[i] = 0.f;
    }

    int beg = offs[node], end = offs[node + 1];
    for (int e = beg + slot; e < end; e += 8) {
        int s = csr_src[e];
        half8 v = *(const half8*)&g[(size_t)s * DIM + fbase];
#pragma unroll
        for (int i = 0; i < 8; ++i) acc[i] += (float)v[i];
    }

    // butterfly over the 8 slots (lane bits 3,4,5)
#pragma unroll
    for (int m = 8; m <= 32; m <<= 1)
#pragma unroll
        for (int i = 0; i < 8; ++i) acc[i] += __shfl_xor(acc[i], m, 64);

    if (slot == 0) {
        float dd = dinv[node];
        float4 b0 = *(const float4*)&bias[fbase];
        float4 b1 = *(const float4*)&bias[fbase + 4];
        float bb[8] = {b0.x, b0.y, b0.z, b0.w, b1.x, b1.y, b1.z, b1.w};
        half8 o;
#pragma unroll
        for (int i = 0; i < 8; ++i) o[i] = (_Float16)fmaxf(fmaf(dd, acc[i], bb[i]), 0.f);
        *(half8*)&out[(size_t)node * DIM + fbase] = o;
    }
}

// ---------------------------------------------------------------- max pool
__global__ __launch_bounds__(256) void k_maxpool(const _Float16* __restrict__ x,
                                                 float* __restrict__ out) {
    __shared__ float lmax[4][DIM];
    int stream = threadIdx.x >> 6, lane = threadIdx.x & 63;
    int f0 = lane * 8;
    int r0 = blockIdx.x * MAXP_ROWS;
    int r1 = min(r0 + MAXP_ROWS, N_NODES);

    float m[8];
#pragma unroll
    for (int i = 0; i < 8; ++i) m[i] = 0.f;
    for (int r = r0 + stream; r < r1; r += 4) {
        half8 v = *(const half8*)&x[(size_t)r * DIM + f0];
#pragma unroll
        for (int i = 0; i < 8; ++i) m[i] = fmaxf(m[i], (float)v[i]);
    }
#pragma unroll
    for (int i = 0; i < 8; ++i) lmax[stream][f0 + i] = m[i];
    __syncthreads();
#pragma unroll
    for (int rep = 0; rep < 2; ++rep) {
        int f = rep * 256 + threadIdx.x;
        float v = fmaxf(fmaxf(lmax[0][f], lmax[1][f]), fmaxf(lmax[2][f], lmax[3][f]));
        atomicMax((int*)&out[f], __float_as_int(v));  // post-ReLU >= 0: int cmp == float cmp
    }
}

// ---------------------------------------------------------------- launch
extern "C" void kernel_launch(void* const* d_in, const int* in_sizes, int n_in,
                              void* d_out, int out_size, void* d_ws, size_t ws_size,
                              hipStream_t stream) {
    const float* features = (const float*)d_in[0];
    const int*   ei       = (const int*)d_in[1];
    const float* W1       = (const float*)d_in[3];
    const float* b1       = (const float*)d_in[4];
    const float* W2       = (const float*)d_in[5];
    const float* b2       = (const float*)d_in[6];
    float* out = (float*)d_out;

    const int* src = ei;
    const int* dst = ei + N_EDGES;

    char* p = (char*)d_ws;
    auto alloc = [&](size_t bytes) { void* r = p; p += (bytes + 255) & ~(size_t)255; return r; };
    int*      cnt    = (int*)alloc(N_NODES * 4);
    int*      offs   = (int*)alloc((N_NODES + 1) * 4);
    int*      cursor = (int*)alloc(N_NODES * 4);
    float*    dinv   = (float*)alloc(MP * 4);
    int*      csr    = (int*)alloc(N_EDGES * 4);
    int*      bsum   = (int*)alloc(SCAN_BLOCKS * 4);
    int*      bbase  = (int*)alloc(SCAN_BLOCKS * 4);
    _Float16* fA   = (_Float16*)alloc((size_t)MP * DIM * 2);
    _Float16* Wt1  = (_Float16*)alloc((size_t)DIM * DIM * 2);
    _Float16* Wt2  = (_Float16*)alloc((size_t)DIM * DIM * 2);
    _Float16* gbuf = (_Float16*)alloc((size_t)MP * DIM * 2);
    _Float16* x1f  = (_Float16*)alloc((size_t)MP * DIM * 2);
    _Float16* x2h  = (_Float16*)alloc((size_t)MP * DIM * 2);

    // --- zero cnt + out
    hipMemsetAsync(cnt, 0, N_NODES * 4, stream);
    hipMemsetAsync(out, 0, DIM * 4, stream);

    // --- graph norm + CSR build
    k_count<<<FILL_BLOCKS, 256, 0, stream>>>(dst, cnt);
    k_scan_a<<<SCAN_BLOCKS, 256, 0, stream>>>(cnt, bsum);
    k_scan_b<<<1, 128, 0, stream>>>(bsum, bbase);
    k_scan_c<<<SCAN_BLOCKS, 256, 0, stream>>>(cnt, bbase, offs, cursor, dinv);

    // --- fused: CSR fill + feature f16 cvt + W transposes
    k_prep<<<FILL_BLOCKS + CVT_BLOCKS + W_BLOCKS, 256, 0, stream>>>(
        src, dst, cursor, csr, features, fA, W1, W2, Wt1, Wt2);

    dim3 ggrd(MP / 128, DIM / 128);

    // --- layer 1  (agg grid: 8 chunks x MP/4 node-groups)
    k_gemm_f16<<<ggrd, 256, 0, stream>>>(fA, Wt1, dinv, gbuf);
    k_agg_x<<<8 * (MP / 4), 256, 0, stream>>>(gbuf, dinv, offs, csr, b1, x1f, MP);

    // --- layer 2  (20000/4 = 5000 node-groups exactly)
    k_gemm_f16<<<ggrd, 256, 0, stream>>>(x1f, Wt2, dinv, gbuf);
    k_agg_x<<<8 * (N_NODES / 4), 256, 0, stream>>>(gbuf, dinv, offs, csr, b2, x2h, N_NODES);

    // --- global max pool (out zeroed by memset)
    k_maxpool<<<MAXP_BLOCKS, 256, 0, stream>>>(x2h, out);
}

// Round 8
// 301.503 us; speedup vs baseline: 1.0377x; 1.0377x over previous
//
#include <hip/hip_runtime.h>

#define N_NODES 20000
#define MP      20096   // N_NODES padded to multiple of 128
#define N_EDGES 320000
#define DIM     512
#define SCAN_BLOCKS 79    // ceil(20224/256)
#define FILL_BLOCKS 1250  // N_EDGES/256
#define CVT_BLOCKS  10048 // MP*DIM/4/256
#define W_BLOCKS    512   // 16x16 tiles x 2 weights
#define SORT_BLOCKS 79
#define MAXP_BLOCKS 256
#define MAXP_ROWS   79    // ceil(20000/256)

typedef _Float16 half8 __attribute__((ext_vector_type(8)));
typedef _Float16 half4v __attribute__((ext_vector_type(4)));
typedef float floatx4 __attribute__((ext_vector_type(4)));

#define GLD16(g, l) __builtin_amdgcn_global_load_lds( \
    (const __attribute__((address_space(1))) unsigned int*)(g), \
    (__attribute__((address_space(3))) unsigned int*)(l), 16, 0, 0)

__global__ void k_count(const int* __restrict__ dst, int* __restrict__ cnt) {
    int e = blockIdx.x * blockDim.x + threadIdx.x;
    if (e < N_EDGES) atomicAdd(&cnt[dst[e]], 1);
}

// ---------------------------------------------------------------- parallel scan
__global__ __launch_bounds__(256) void k_scan_a(const int* __restrict__ cnt,
                                                int* __restrict__ bsum) {
    __shared__ int buf[256];
    int gi = blockIdx.x * 256 + threadIdx.x;
    buf[threadIdx.x] = (gi < N_NODES) ? cnt[gi] : 0;
    __syncthreads();
    for (int off = 128; off > 0; off >>= 1) {
        if (threadIdx.x < off) buf[threadIdx.x] += buf[threadIdx.x + off];
        __syncthreads();
    }
    if (threadIdx.x == 0) bsum[blockIdx.x] = buf[0];
}

__global__ __launch_bounds__(128) void k_scan_b(const int* __restrict__ bsum,
                                                int* __restrict__ bbase) {
    __shared__ int buf[128];
    int tid = threadIdx.x;
    int v = (tid < SCAN_BLOCKS) ? bsum[tid] : 0;
    buf[tid] = v;
    __syncthreads();
    for (int off = 1; off < 128; off <<= 1) {
        int t = (tid >= off) ? buf[tid - off] : 0;
        __syncthreads();
        buf[tid] += t;
        __syncthreads();
    }
    if (tid < SCAN_BLOCKS) bbase[tid] = buf[tid] - v;  // exclusive
}

// offs/cursor/dinv + degree histogram (for the counting sort)
__global__ __launch_bounds__(256) void k_scan_c(const int* __restrict__ cnt,
                                                const int* __restrict__ bbase,
                                                int* __restrict__ offs,
                                                int* __restrict__ cursor,
                                                float* __restrict__ dinv,
                                                int* __restrict__ hist) {
    __shared__ int buf[256];
    __shared__ int lh[256];
    int tid = threadIdx.x;
    int gi = blockIdx.x * 256 + tid;
    int v = (gi < N_NODES) ? cnt[gi] : 0;
    buf[tid] = v;
    lh[tid] = 0;
    __syncthreads();
    for (int off = 1; off < 256; off <<= 1) {
        int t = (tid >= off) ? buf[tid - off] : 0;
        __syncthreads();
        buf[tid] += t;
        __syncthreads();
    }
    int base = bbase[blockIdx.x];
    if (gi < N_NODES) {
        int incl = base + buf[tid];
        offs[gi + 1] = incl;
        cursor[gi] = incl - v;
        dinv[gi] = rsqrtf((float)v + 1.0f);  // +1 self-loop
        if (gi == 0) offs[0] = 0;
        atomicAdd(&lh[v > 255 ? 255 : v], 1);  // LDS-local degree histogram
    } else if (gi < MP) {
        dinv[gi] = 0.f;  // pad rows: zero (poison-proofs GEMM epilogue)
    }
    __syncthreads();
    if (lh[tid]) atomicAdd(&hist[tid], lh[tid]);
}

// ---------------------------------------------------------------- fused prep
// [0,1250): CSR fill; [1250,11298): feature cvt; [11298,11810): W transpose;
// [11810,11889): degree-counting-sort scatter (sort order is a perf heuristic only)
__global__ __launch_bounds__(256) void k_prep(const int* __restrict__ src,
                                              const int* __restrict__ dst,
                                              int* __restrict__ cursor,
                                              int* __restrict__ csr_src,
                                              const float* __restrict__ F,
                                              _Float16* __restrict__ A,
                                              const float* __restrict__ W1,
                                              const float* __restrict__ W2,
                                              _Float16* __restrict__ Wt1,
                                              _Float16* __restrict__ Wt2,
                                              const int* __restrict__ cnt,
                                              const int* __restrict__ hist,
                                              int* __restrict__ bincur,
                                              int* __restrict__ sorted) {
    int b = blockIdx.x;
    if (b < FILL_BLOCKS) {
        int e = b * 256 + threadIdx.x;
        int d = dst[e];
        int pos = atomicAdd(&cursor[d], 1);
        csr_src[pos] = src[e];
        return;
    }
    if (b < FILL_BLOCKS + CVT_BLOCKS) {
        int i = (b - FILL_BLOCKS) * 256 + threadIdx.x;  // over MP*DIM/4
        int e = i * 4;
        int row = e >> 9;
        half4v o;
        if (row < N_NODES) {
            float4 v = *(const float4*)&F[e];
            o[0] = (_Float16)v.x; o[1] = (_Float16)v.y;
            o[2] = (_Float16)v.z; o[3] = (_Float16)v.w;
        } else {
            o[0] = o[1] = o[2] = o[3] = (_Float16)0.f;
        }
        *(half4v*)&A[e] = o;
        return;
    }
    if (b < FILL_BLOCKS + CVT_BLOCKS + W_BLOCKS) {
        // W transpose: fp32 [k][n] -> f16 [n][k]
        int local = b - (FILL_BLOCKS + CVT_BLOCKS);
        int z = local >> 8, t = local & 255;
        const float* W = z ? W2 : W1;
        _Float16* Wt = z ? Wt2 : Wt1;
        __shared__ float tile[32][33];
        int bx = (t & 15) * 32, by = (t >> 4) * 32;
        int x = threadIdx.x & 31, y4 = (threadIdx.x >> 5) * 4;
#pragma unroll
        for (int r = 0; r < 4; ++r)
            tile[y4 + r][x] = W[(size_t)(by + y4 + r) * DIM + bx + x];
        __syncthreads();
#pragma unroll
        for (int r = 0; r < 4; ++r)
            Wt[(size_t)(bx + y4 + r) * DIM + by + x] = (_Float16)tile[x][y4 + r];
        return;
    }
    // counting-sort scatter: every block redundantly scans the 256-bin histogram
    int sb = b - (FILL_BLOCKS + CVT_BLOCKS + W_BLOCKS);
    __shared__ int sc[256];
    int tid = threadIdx.x;
    int hv = hist[tid];
    sc[tid] = hv;
    __syncthreads();
    for (int off = 1; off < 256; off <<= 1) {
        int t = (tid >= off) ? sc[tid - off] : 0;
        __syncthreads();
        sc[tid] += t;
        __syncthreads();
    }
    int base = sc[tid] - hv;  // exclusive base of bin tid
    __syncthreads();
    sc[tid] = base;
    __syncthreads();
    int gi = sb * 256 + tid;
    if (gi < N_NODES) {
        int d = cnt[gi];
        int bin = d > 255 ? 255 : d;
        int pos = sc[bin] + atomicAdd(&bincur[bin], 1);
        sorted[pos] = gi;
    } else if (gi < MP) {
        sorted[gi] = gi;  // pad ids land at [N_NODES, MP)
    }
}

// ---------------------------------------------------------------- MFMA GEMM
// g[MP,512] f16 = dinv[row] * (A[MP,512] f16 @ Bt[n][k] f16)
__global__ __launch_bounds__(256) void k_gemm_f16(const _Float16* __restrict__ A,
                                                  const _Float16* __restrict__ Bt,
                                                  const float* __restrict__ dinv,
                                                  _Float16* __restrict__ G) {
    __shared__ _Float16 As[128 * 32];  // [m][k], k contiguous
    __shared__ _Float16 Bs[128 * 32];  // [n][k], k contiguous

    int t = threadIdx.x;
    int w = t >> 6, lane = t & 63;
    int lm = lane & 15, quad = lane >> 4;
    int m0 = blockIdx.x * 128, n0 = blockIdx.y * 128;
    int wm = (w & 1) * 64, wn = (w >> 1) * 64;

    floatx4 acc[4][4];
#pragma unroll
    for (int i = 0; i < 4; ++i)
#pragma unroll
        for (int j = 0; j < 4; ++j) acc[i][j] = (floatx4){0.f, 0.f, 0.f, 0.f};

    for (int k0 = 0; k0 < DIM; k0 += 32) {
        __syncthreads();
#pragma unroll
        for (int i = 0; i < 2; ++i) {
            int s = i * 256 + t;
            int m = s >> 2, kk = (s & 3) * 8;
            GLD16(A + (size_t)(m0 + m) * DIM + k0 + kk, As + s * 8);
            GLD16(Bt + (size_t)(n0 + m) * DIM + k0 + kk, Bs + s * 8);
        }
        __syncthreads();

        half8 af[4], bf[4];
#pragma unroll
        for (int i = 0; i < 4; ++i)
            af[i] = *(const half8*)&As[(wm + i * 16 + lm) * 32 + quad * 8];
#pragma unroll
        for (int j = 0; j < 4; ++j)
            bf[j] = *(const half8*)&Bs[(wn + j * 16 + lm) * 32 + quad * 8];
#pragma unroll
        for (int i = 0; i < 4; ++i)
#pragma unroll
            for (int j = 0; j < 4; ++j)
                acc[i][j] = __builtin_amdgcn_mfma_f32_16x16x32_f16(af[i], bf[j], acc[i][j], 0, 0, 0);
    }

#pragma unroll
    for (int i = 0; i < 4; ++i)
#pragma unroll
        for (int r = 0; r < 4; ++r) {
            int row = m0 + wm + i * 16 + quad * 4 + r;
            float dd = dinv[row];  // 0 on pad rows
#pragma unroll
            for (int j = 0; j < 4; ++j) {
                int col = n0 + wn + j * 16 + lm;
                G[(size_t)row * DIM + col] = (_Float16)(dd * acc[i][j][r]);
            }
        }
}

// ---------------------------------------------------------------- aggregation
// XCD-affine feature-chunked gather (chunk = blockIdx&7 -> 2.57MB slab per XCD L2)
// + serial per-node edge loops: wave = 8 nodes x 64 features; each 8-lane octet
// owns one node (degree-sorted -> uniform trip counts), accumulates in registers,
// no cross-lane reduce, no LDS. One 1KB load per wave-iteration (8 rows x 128B).
__global__ __launch_bounds__(256) void k_agg_s(const _Float16* __restrict__ g,
                                               const float* __restrict__ dinv,
                                               const int* __restrict__ offs,
                                               const int* __restrict__ csr_src,
                                               const int* __restrict__ sorted,
                                               const float* __restrict__ bias,
                                               _Float16* __restrict__ out) {
    int chunk = blockIdx.x & 7;
    int grp = blockIdx.x >> 3;                 // 0..627
    int w = threadIdx.x >> 6, lane = threadIdx.x & 63;
    int slot = lane >> 3, fg = lane & 7;
    int idx = grp * 32 + w * 8 + slot;         // 0..MP-1 exactly (628*32 = 20096)
    int node = sorted[idx];
    int fbase = chunk * 64 + fg * 8;
    size_t obase = (size_t)node * DIM + fbase;

    if (node >= N_NODES) {  // pad row: zero this 16B (x1f feeds GEMM2's A)
        half8 z;
#pragma unroll
        for (int i = 0; i < 8; ++i) z[i] = (_Float16)0.f;
        *(half8*)&out[obase] = z;
        return;
    }

    float acc[8];
    half8 self = *(const half8*)&g[obase];
#pragma unroll
    for (int i = 0; i < 8; ++i) acc[i] = (float)self[i];

    int beg = offs[node], end = offs[node + 1];
    int e = beg;
    for (; e + 4 <= end; e += 4) {
        int s0 = csr_src[e], s1 = csr_src[e + 1], s2 = csr_src[e + 2], s3 = csr_src[e + 3];
        half8 v0 = *(const half8*)&g[(size_t)s0 * DIM + fbase];
        half8 v1 = *(const half8*)&g[(size_t)s1 * DIM + fbase];
        half8 v2 = *(const half8*)&g[(size_t)s2 * DIM + fbase];
        half8 v3 = *(const half8*)&g[(size_t)s3 * DIM + fbase];
#pragma unroll
        for (int i = 0; i < 8; ++i)
            acc[i] += ((float)v0[i] + (float)v1[i]) + ((float)v2[i] + (float)v3[i]);
    }
    for (; e < end; ++e) {
        int s = csr_src[e];
        half8 v = *(const half8*)&g[(size_t)s * DIM + fbase];
#pragma unroll
        for (int i = 0; i < 8; ++i) acc[i] += (float)v[i];
    }

    float dd = dinv[node];
    float4 b0 = *(const float4*)&bias[fbase];
    float4 b1 = *(const float4*)&bias[fbase + 4];
    float bb[8] = {b0.x, b0.y, b0.z, b0.w, b1.x, b1.y, b1.z, b1.w};
    half8 o;
#pragma unroll
    for (int i = 0; i < 8; ++i) o[i] = (_Float16)fmaxf(fmaf(dd, acc[i], bb[i]), 0.f);
    *(half8*)&out[obase] = o;
}

// ---------------------------------------------------------------- max pool
__global__ __launch_bounds__(256) void k_maxpool(const _Float16* __restrict__ x,
                                                 float* __restrict__ out) {
    __shared__ float lmax[4][DIM];
    int stream = threadIdx.x >> 6, lane = threadIdx.x & 63;
    int f0 = lane * 8;
    int r0 = blockIdx.x * MAXP_ROWS;
    int r1 = min(r0 + MAXP_ROWS, N_NODES);

    float m[8];
#pragma unroll
    for (int i = 0; i < 8; ++i) m[i] = 0.f;
    for (int r = r0 + stream; r < r1; r += 4) {
        half8 v = *(const half8*)&x[(size_t)r * DIM + f0];
#pragma unroll
        for (int i = 0; i < 8; ++i) m[i] = fmaxf(m[i], (float)v[i]);
    }
#pragma unroll
    for (int i = 0; i < 8; ++i) lmax[stream][f0 + i] = m[i];
    __syncthreads();
#pragma unroll
    for (int rep = 0; rep < 2; ++rep) {
        int f = rep * 256 + threadIdx.x;
        float v = fmaxf(fmaxf(lmax[0][f], lmax[1][f]), fmaxf(lmax[2][f], lmax[3][f]));
        atomicMax((int*)&out[f], __float_as_int(v));  // post-ReLU >= 0: int cmp == float cmp
    }
}

// ---------------------------------------------------------------- launch
extern "C" void kernel_launch(void* const* d_in, const int* in_sizes, int n_in,
                              void* d_out, int out_size, void* d_ws, size_t ws_size,
                              hipStream_t stream) {
    const float* features = (const float*)d_in[0];
    const int*   ei       = (const int*)d_in[1];
    const float* W1       = (const float*)d_in[3];
    const float* b1       = (const float*)d_in[4];
    const float* W2       = (const float*)d_in[5];
    const float* b2       = (const float*)d_in[6];
    float* out = (float*)d_out;

    const int* src = ei;
    const int* dst = ei + N_EDGES;

    char* p = (char*)d_ws;
    auto alloc = [&](size_t bytes) { void* r = p; p += (bytes + 255) & ~(size_t)255; return r; };
    // zero-region: cnt + hist + bincur (single memset)
    int*      cnt    = (int*)alloc(N_NODES * 4);
    int*      hist   = (int*)alloc(256 * 4);
    int*      bincur = (int*)alloc(256 * 4);
    char*     zeroEnd = p;
    int*      offs   = (int*)alloc((N_NODES + 1) * 4);
    int*      cursor = (int*)alloc(N_NODES * 4);
    float*    dinv   = (float*)alloc(MP * 4);
    int*      csr    = (int*)alloc(N_EDGES * 4);
    int*      bsum   = (int*)alloc(SCAN_BLOCKS * 4);
    int*      bbase  = (int*)alloc(SCAN_BLOCKS * 4);
    int*      sorted = (int*)alloc(MP * 4);
    _Float16* fA   = (_Float16*)alloc((size_t)MP * DIM * 2);
    _Float16* Wt1  = (_Float16*)alloc((size_t)DIM * DIM * 2);
    _Float16* Wt2  = (_Float16*)alloc((size_t)DIM * DIM * 2);
    _Float16* gbuf = (_Float16*)alloc((size_t)MP * DIM * 2);
    _Float16* x1f  = (_Float16*)alloc((size_t)MP * DIM * 2);
    _Float16* x2h  = (_Float16*)alloc((size_t)MP * DIM * 2);

    // --- zero cnt/hist/bincur + out
    hipMemsetAsync(cnt, 0, (size_t)(zeroEnd - (char*)cnt), stream);
    hipMemsetAsync(out, 0, DIM * 4, stream);

    // --- graph norm + CSR build
    k_count<<<FILL_BLOCKS, 256, 0, stream>>>(dst, cnt);
    k_scan_a<<<SCAN_BLOCKS, 256, 0, stream>>>(cnt, bsum);
    k_scan_b<<<1, 128, 0, stream>>>(bsum, bbase);
    k_scan_c<<<SCAN_BLOCKS, 256, 0, stream>>>(cnt, bbase, offs, cursor, dinv, hist);

    // --- fused: CSR fill + feature f16 cvt + W transposes + degree sort
    k_prep<<<FILL_BLOCKS + CVT_BLOCKS + W_BLOCKS + SORT_BLOCKS, 256, 0, stream>>>(
        src, dst, cursor, csr, features, fA, W1, W2, Wt1, Wt2, cnt, hist, bincur, sorted);

    dim3 ggrd(MP / 128, DIM / 128);

    // --- layer 1
    k_gemm_f16<<<ggrd, 256, 0, stream>>>(fA, Wt1, dinv, gbuf);
    k_agg_s<<<8 * (MP / 32), 256, 0, stream>>>(gbuf, dinv, offs, csr, sorted, b1, x1f);

    // --- layer 2
    k_gemm_f16<<<ggrd, 256, 0, stream>>>(x1f, Wt2, dinv, gbuf);
    k_agg_s<<<8 * (MP / 32), 256, 0, stream>>>(gbuf, dinv, offs, csr, sorted, b2, x2h);

    // --- global max pool (out zeroed by memset)
    k_maxpool<<<MAXP_BLOCKS, 256, 0, stream>>>(x2h, out);
}

// Round 10
// 263.803 us; speedup vs baseline: 1.1860x; 1.1429x over previous
//
#include <hip/hip_runtime.h>

#define N_NODES 20000
#define MP      20096   // N_NODES padded to multiple of 128
#define N_EDGES 320000
#define DIM     512
#define SCAN_BLOCKS 79    // ceil(20224/256)
#define FILL_BLOCKS 1250  // N_EDGES/256
#define CVT_BLOCKS  2512  // MP*DIM/4 items / 1024 per block
#define W_BLOCKS    512   // 16x16 tiles x 2 weights
#define SORT_BLOCKS 79
#define NBIN 4096         // 256 degree bins x 16 sub-bins (shortens atomic chains)
#define MAXP_BLOCKS 256
#define MAXP_ROWS   79    // ceil(20000/256)

typedef _Float16 half8 __attribute__((ext_vector_type(8)));
typedef _Float16 half4v __attribute__((ext_vector_type(4)));
typedef float floatx4 __attribute__((ext_vector_type(4)));

#define GLD16(g, l) __builtin_amdgcn_global_load_lds( \
    (const __attribute__((address_space(1))) unsigned int*)(g), \
    (__attribute__((address_space(3))) unsigned int*)(l), 16, 0, 0)

__global__ void k_count(const int* __restrict__ dst, int* __restrict__ cnt) {
    int e = blockIdx.x * blockDim.x + threadIdx.x;
    if (e < N_EDGES) atomicAdd(&cnt[dst[e]], 1);
}

// ---------------------------------------------------------------- parallel scan
__global__ __launch_bounds__(256) void k_scan_a(const int* __restrict__ cnt,
                                                int* __restrict__ bsum) {
    __shared__ int buf[256];
    int gi = blockIdx.x * 256 + threadIdx.x;
    buf[threadIdx.x] = (gi < N_NODES) ? cnt[gi] : 0;
    __syncthreads();
    for (int off = 128; off > 0; off >>= 1) {
        if (threadIdx.x < off) buf[threadIdx.x] += buf[threadIdx.x + off];
        __syncthreads();
    }
    if (threadIdx.x == 0) bsum[blockIdx.x] = buf[0];
}

__global__ __launch_bounds__(128) void k_scan_b(const int* __restrict__ bsum,
                                                int* __restrict__ bbase) {
    __shared__ int buf[128];
    int tid = threadIdx.x;
    int v = (tid < SCAN_BLOCKS) ? bsum[tid] : 0;
    buf[tid] = v;
    __syncthreads();
    for (int off = 1; off < 128; off <<= 1) {
        int t = (tid >= off) ? buf[tid - off] : 0;
        __syncthreads();
        buf[tid] += t;
        __syncthreads();
    }
    if (tid < SCAN_BLOCKS) bbase[tid] = buf[tid] - v;  // exclusive
}

// offs/cursor/dinv + sub-binned degree histogram (for the counting sort)
__global__ __launch_bounds__(256) void k_scan_c(const int* __restrict__ cnt,
                                                const int* __restrict__ bbase,
                                                int* __restrict__ offs,
                                                int* __restrict__ cursor,
                                                float* __restrict__ dinv,
                                                int* __restrict__ hist) {
    __shared__ int buf[256];
    __shared__ int lh[NBIN];
    int tid = threadIdx.x;
#pragma unroll
    for (int k = 0; k < NBIN / 256; ++k) lh[tid + k * 256] = 0;
    int gi = blockIdx.x * 256 + tid;
    int v = (gi < N_NODES) ? cnt[gi] : 0;
    buf[tid] = v;
    __syncthreads();
    for (int off = 1; off < 256; off <<= 1) {
        int t = (tid >= off) ? buf[tid - off] : 0;
        __syncthreads();
        buf[tid] += t;
        __syncthreads();
    }
    int base = bbase[blockIdx.x];
    if (gi < N_NODES) {
        int incl = base + buf[tid];
        offs[gi + 1] = incl;
        cursor[gi] = incl - v;
        dinv[gi] = rsqrtf((float)v + 1.0f);  // +1 self-loop
        if (gi == 0) offs[0] = 0;
        int bin = (v > 255 ? 255 : v) * 16 + (gi & 15);
        atomicAdd(&lh[bin], 1);
    } else if (gi < MP) {
        dinv[gi] = 0.f;  // pad rows: zero (poison-proofs GEMM epilogue)
    }
    __syncthreads();
#pragma unroll
    for (int k = 0; k < NBIN / 256; ++k) {
        int b2 = tid + k * 256;
        if (lh[b2]) atomicAdd(&hist[b2], lh[b2]);
    }
}

// ---------------------------------------------------------------- fused prep
// [0,1250): CSR fill; [1250,3762): feature cvt (x4 grid-stride);
// [3762,4274): W transpose; [4274,4353): counting-sort scatter (R8-proven
// single-level atomic form; 16 sub-bins shorten same-address chains ~16x).
// Sort order is a perf heuristic only — correctness never depends on it.
__global__ __launch_bounds__(256) void k_prep(const int* __restrict__ src,
                                              const int* __restrict__ dst,
                                              int* __restrict__ cursor,
                                              int* __restrict__ csr_src,
                                              const float* __restrict__ F,
                                              _Float16* __restrict__ A,
                                              const float* __restrict__ W1,
                                              const float* __restrict__ W2,
                                              _Float16* __restrict__ Wt1,
                                              _Float16* __restrict__ Wt2,
                                              const int* __restrict__ cnt,
                                              const int* __restrict__ hist,
                                              int* __restrict__ bincur,
                                              int* __restrict__ sorted) {
    int b = blockIdx.x;
    if (b < FILL_BLOCKS) {
        int e = b * 256 + threadIdx.x;
        int d = dst[e];
        int pos = atomicAdd(&cursor[d], 1);
        csr_src[pos] = src[e];
        return;
    }
    if (b < FILL_BLOCKS + CVT_BLOCKS) {
        int base = (b - FILL_BLOCKS) * 1024 + threadIdx.x;  // 4 float4s per thread
#pragma unroll
        for (int k = 0; k < 4; ++k) {
            int i = base + k * 256;
            int e = i * 4;
            int row = e >> 9;
            half4v o;
            if (row < N_NODES) {
                float4 v = *(const float4*)&F[e];
                o[0] = (_Float16)v.x; o[1] = (_Float16)v.y;
                o[2] = (_Float16)v.z; o[3] = (_Float16)v.w;
            } else {
                o[0] = o[1] = o[2] = o[3] = (_Float16)0.f;
            }
            *(half4v*)&A[e] = o;
        }
        return;
    }
    if (b < FILL_BLOCKS + CVT_BLOCKS + W_BLOCKS) {
        // W transpose: fp32 [k][n] -> f16 [n][k]
        int local = b - (FILL_BLOCKS + CVT_BLOCKS);
        int z = local >> 8, t = local & 255;
        const float* W = z ? W2 : W1;
        _Float16* Wt = z ? Wt2 : Wt1;
        __shared__ float tile[32][33];
        int bx = (t & 15) * 32, by = (t >> 4) * 32;
        int x = threadIdx.x & 31, y4 = (threadIdx.x >> 5) * 4;
#pragma unroll
        for (int r = 0; r < 4; ++r)
            tile[y4 + r][x] = W[(size_t)(by + y4 + r) * DIM + bx + x];
        __syncthreads();
#pragma unroll
        for (int r = 0; r < 4; ++r)
            Wt[(size_t)(bx + y4 + r) * DIM + by + x] = (_Float16)tile[x][y4 + r];
        return;
    }
    // --- counting-sort scatter (single-level, R8-proven)
    int sb = b - (FILL_BLOCKS + CVT_BLOCKS + W_BLOCKS);
    __shared__ int sc[NBIN];  // global exclusive base per bin
    __shared__ int ps[256];
    int tid = threadIdx.x;
    int tsum = 0;
#pragma unroll
    for (int k = 0; k < NBIN / 256; ++k) {
        int h = hist[tid * (NBIN / 256) + k];
        sc[tid * (NBIN / 256) + k] = tsum;  // exclusive within this thread's group
        tsum += h;
    }
    ps[tid] = tsum;
    __syncthreads();
    for (int off = 1; off < 256; off <<= 1) {
        int t = (tid >= off) ? ps[tid - off] : 0;
        __syncthreads();
        ps[tid] += t;
        __syncthreads();
    }
    int gbase = ps[tid] - tsum;  // exclusive prefix of this thread's bin group
#pragma unroll
    for (int k = 0; k < NBIN / 256; ++k) sc[tid * (NBIN / 256) + k] += gbase;
    __syncthreads();
    int gi = sb * 256 + tid;
    if (gi < N_NODES) {
        int d = cnt[gi];
        int bin = (d > 255 ? 255 : d) * 16 + (gi & 15);
        int pos = sc[bin] + atomicAdd(&bincur[bin], 1);
        sorted[pos] = gi;
    } else if (gi < MP) {
        sorted[gi] = gi;  // pad ids land at [N_NODES, MP)
    }
}

// ---------------------------------------------------------------- MFMA GEMM
// g[MP,512] f16 = dinv[row] * (A[MP,512] f16 @ Bt[n][k] f16)
__global__ __launch_bounds__(256) void k_gemm_f16(const _Float16* __restrict__ A,
                                                  const _Float16* __restrict__ Bt,
                                                  const float* __restrict__ dinv,
                                                  _Float16* __restrict__ G) {
    __shared__ _Float16 As[128 * 32];  // [m][k], k contiguous
    __shared__ _Float16 Bs[128 * 32];  // [n][k], k contiguous

    int t = threadIdx.x;
    int w = t >> 6, lane = t & 63;
    int lm = lane & 15, quad = lane >> 4;
    int m0 = blockIdx.x * 128, n0 = blockIdx.y * 128;
    int wm = (w & 1) * 64, wn = (w >> 1) * 64;

    floatx4 acc[4][4];
#pragma unroll
    for (int i = 0; i < 4; ++i)
#pragma unroll
        for (int j = 0; j < 4; ++j) acc[i][j] = (floatx4){0.f, 0.f, 0.f, 0.f};

    for (int k0 = 0; k0 < DIM; k0 += 32) {
        __syncthreads();
#pragma unroll
        for (int i = 0; i < 2; ++i) {
            int s = i * 256 + t;
            int m = s >> 2, kk = (s & 3) * 8;
            GLD16(A + (size_t)(m0 + m) * DIM + k0 + kk, As + s * 8);
            GLD16(Bt + (size_t)(n0 + m) * DIM + k0 + kk, Bs + s * 8);
        }
        __syncthreads();

        half8 af[4], bf[4];
#pragma unroll
        for (int i = 0; i < 4; ++i)
            af[i] = *(const half8*)&As[(wm + i * 16 + lm) * 32 + quad * 8];
#pragma unroll
        for (int j = 0; j < 4; ++j)
            bf[j] = *(const half8*)&Bs[(wn + j * 16 + lm) * 32 + quad * 8];
#pragma unroll
        for (int i = 0; i < 4; ++i)
#pragma unroll
            for (int j = 0; j < 4; ++j)
                acc[i][j] = __builtin_amdgcn_mfma_f32_16x16x32_f16(af[i], bf[j], acc[i][j], 0, 0, 0);
    }

#pragma unroll
    for (int i = 0; i < 4; ++i)
#pragma unroll
        for (int r = 0; r < 4; ++r) {
            int row = m0 + wm + i * 16 + quad * 4 + r;
            float dd = dinv[row];  // 0 on pad rows
#pragma unroll
            for (int j = 0; j < 4; ++j) {
                int col = n0 + wn + j * 16 + lm;
                G[(size_t)row * DIM + col] = (_Float16)(dd * acc[i][j][r]);
            }
        }
}

// ---------------------------------------------------------------- aggregation
// XCD-affine feature-chunked gather (chunk = blockIdx&7 -> 2.57MB slab per XCD L2)
// + serial per-node edge loops: wave = 8 nodes x 64 features; each 8-lane octet
// owns one node (degree-sorted -> uniform trip counts), accumulates in registers.
// Unroll x8 -> 8 outstanding L2 gathers per octet.
__global__ __launch_bounds__(256) void k_agg_s(const _Float16* __restrict__ g,
                                               const float* __restrict__ dinv,
                                               const int* __restrict__ offs,
                                               const int* __restrict__ csr_src,
                                               const int* __restrict__ sorted,
                                               const float* __restrict__ bias,
                                               _Float16* __restrict__ out) {
    int chunk = blockIdx.x & 7;
    int grp = blockIdx.x >> 3;                 // 0..627
    int w = threadIdx.x >> 6, lane = threadIdx.x & 63;
    int slot = lane >> 3, fg = lane & 7;
    int idx = grp * 32 + w * 8 + slot;         // 0..MP-1 exactly (628*32 = 20096)
    int node = sorted[idx];
    if ((unsigned)node >= (unsigned)MP) return;  // defensive: never scribble OOB
    int fbase = chunk * 64 + fg * 8;
    size_t obase = (size_t)node * DIM + fbase;

    if (node >= N_NODES) {  // pad row: zero this 16B (x1f feeds GEMM2's A)
        half8 z;
#pragma unroll
        for (int i = 0; i < 8; ++i) z[i] = (_Float16)0.f;
        *(half8*)&out[obase] = z;
        return;
    }

    float acc[8];
    half8 self = *(const half8*)&g[obase];
#pragma unroll
    for (int i = 0; i < 8; ++i) acc[i] = (float)self[i];

    int beg = offs[node], end = offs[node + 1];
    int e = beg;
    for (; e + 8 <= end; e += 8) {
        int s0 = csr_src[e],     s1 = csr_src[e + 1], s2 = csr_src[e + 2], s3 = csr_src[e + 3];
        int s4 = csr_src[e + 4], s5 = csr_src[e + 5], s6 = csr_src[e + 6], s7 = csr_src[e + 7];
        half8 v0 = *(const half8*)&g[(size_t)s0 * DIM + fbase];
        half8 v1 = *(const half8*)&g[(size_t)s1 * DIM + fbase];
        half8 v2 = *(const half8*)&g[(size_t)s2 * DIM + fbase];
        half8 v3 = *(const half8*)&g[(size_t)s3 * DIM + fbase];
        half8 v4 = *(const half8*)&g[(size_t)s4 * DIM + fbase];
        half8 v5 = *(const half8*)&g[(size_t)s5 * DIM + fbase];
        half8 v6 = *(const half8*)&g[(size_t)s6 * DIM + fbase];
        half8 v7 = *(const half8*)&g[(size_t)s7 * DIM + fbase];
#pragma unroll
        for (int i = 0; i < 8; ++i)
            acc[i] += (((float)v0[i] + (float)v1[i]) + ((float)v2[i] + (float)v3[i])) +
                      (((float)v4[i] + (float)v5[i]) + ((float)v6[i] + (float)v7[i]));
    }
    for (; e + 4 <= end; e += 4) {
        int s0 = csr_src[e], s1 = csr_src[e + 1], s2 = csr_src[e + 2], s3 = csr_src[e + 3];
        half8 v0 = *(const half8*)&g[(size_t)s0 * DIM + fbase];
        half8 v1 = *(const half8*)&g[(size_t)s1 * DIM + fbase];
        half8 v2 = *(const half8*)&g[(size_t)s2 * DIM + fbase];
        half8 v3 = *(const half8*)&g[(size_t)s3 * DIM + fbase];
#pragma unroll
        for (int i = 0; i < 8; ++i)
            acc[i] += ((float)v0[i] + (float)v1[i]) + ((float)v2[i] + (float)v3[i]);
    }
    for (; e < end; ++e) {
        int s = csr_src[e];
        half8 v = *(const half8*)&g[(size_t)s * DIM + fbase];
#pragma unroll
        for (int i = 0; i < 8; ++i) acc[i] += (float)v[i];
    }

    float dd = dinv[node];
    float4 b0 = *(const float4*)&bias[fbase];
    float4 b1 = *(const float4*)&bias[fbase + 4];
    float bb[8] = {b0.x, b0.y, b0.z, b0.w, b1.x, b1.y, b1.z, b1.w};
    half8 o;
#pragma unroll
    for (int i = 0; i < 8; ++i) o[i] = (_Float16)fmaxf(fmaf(dd, acc[i], bb[i]), 0.f);
    *(half8*)&out[obase] = o;
}

// ---------------------------------------------------------------- max pool
__global__ __launch_bounds__(256) void k_maxpool(const _Float16* __restrict__ x,
                                                 float* __restrict__ out) {
    __shared__ float lmax[4][DIM];
    int stream = threadIdx.x >> 6, lane = threadIdx.x & 63;
    int f0 = lane * 8;
    int r0 = blockIdx.x * MAXP_ROWS;
    int r1 = min(r0 + MAXP_ROWS, N_NODES);

    float m[8];
#pragma unroll
    for (int i = 0; i < 8; ++i) m[i] = 0.f;
    for (int r = r0 + stream; r < r1; r += 4) {
        half8 v = *(const half8*)&x[(size_t)r * DIM + f0];
#pragma unroll
        for (int i = 0; i < 8; ++i) m[i] = fmaxf(m[i], (float)v[i]);
    }
#pragma unroll
    for (int i = 0; i < 8; ++i) lmax[stream][f0 + i] = m[i];
    __syncthreads();
#pragma unroll
    for (int rep = 0; rep < 2; ++rep) {
        int f = rep * 256 + threadIdx.x;
        float v = fmaxf(fmaxf(lmax[0][f], lmax[1][f]), fmaxf(lmax[2][f], lmax[3][f]));
        atomicMax((int*)&out[f], __float_as_int(v));  // post-ReLU >= 0: int cmp == float cmp
    }
}

// ---------------------------------------------------------------- launch
extern "C" void kernel_launch(void* const* d_in, const int* in_sizes, int n_in,
                              void* d_out, int out_size, void* d_ws, size_t ws_size,
                              hipStream_t stream) {
    const float* features = (const float*)d_in[0];
    const int*   ei       = (const int*)d_in[1];
    const float* W1       = (const float*)d_in[3];
    const float* b1       = (const float*)d_in[4];
    const float* W2       = (const float*)d_in[5];
    const float* b2       = (const float*)d_in[6];
    float* out = (float*)d_out;

    const int* src = ei;
    const int* dst = ei + N_EDGES;

    char* p = (char*)d_ws;
    auto alloc = [&](size_t bytes) { void* r = p; p += (bytes + 255) & ~(size_t)255; return r; };
    // zero-region: cnt + hist + bincur (single memset)
    int*      cnt    = (int*)alloc(N_NODES * 4);
    int*      hist   = (int*)alloc(NBIN * 4);
    int*      bincur = (int*)alloc(NBIN * 4);
    char*     zeroEnd = p;
    int*      offs   = (int*)alloc((N_NODES + 1) * 4);
    int*      cursor = (int*)alloc(N_NODES * 4);
    float*    dinv   = (float*)alloc(MP * 4);
    int*      csr    = (int*)alloc(N_EDGES * 4);
    int*      bsum   = (int*)alloc(SCAN_BLOCKS * 4);
    int*      bbase  = (int*)alloc(SCAN_BLOCKS * 4);
    int*      sorted = (int*)alloc(MP * 4);
    _Float16* fA   = (_Float16*)alloc((size_t)MP * DIM * 2);
    _Float16* Wt1  = (_Float16*)alloc((size_t)DIM * DIM * 2);
    _Float16* Wt2  = (_Float16*)alloc((size_t)DIM * DIM * 2);
    _Float16* gbuf = (_Float16*)alloc((size_t)MP * DIM * 2);
    _Float16* x1f  = (_Float16*)alloc((size_t)MP * DIM * 2);
    _Float16* x2h  = (_Float16*)alloc((size_t)MP * DIM * 2);

    // --- zero cnt/hist/bincur + out
    hipMemsetAsync(cnt, 0, (size_t)(zeroEnd - (char*)cnt), stream);
    hipMemsetAsync(out, 0, DIM * 4, stream);

    // --- graph norm + CSR build
    k_count<<<FILL_BLOCKS, 256, 0, stream>>>(dst, cnt);
    k_scan_a<<<SCAN_BLOCKS, 256, 0, stream>>>(cnt, bsum);
    k_scan_b<<<1, 128, 0, stream>>>(bsum, bbase);
    k_scan_c<<<SCAN_BLOCKS, 256, 0, stream>>>(cnt, bbase, offs, cursor, dinv, hist);

    // --- fused: CSR fill + feature f16 cvt + W transposes + degree sort
    k_prep<<<FILL_BLOCKS + CVT_BLOCKS + W_BLOCKS + SORT_BLOCKS, 256, 0, stream>>>(
        src, dst, cursor, csr, features, fA, W1, W2, Wt1, Wt2, cnt, hist, bincur, sorted);

    dim3 ggrd(MP / 128, DIM / 128);

    // --- layer 1
    k_gemm_f16<<<ggrd, 256, 0, stream>>>(fA, Wt1, dinv, gbuf);
    k_agg_s<<<8 * (MP / 32), 256, 0, stream>>>(gbuf, dinv, offs, csr, sorted, b1, x1f);

    // --- layer 2
    k_gemm_f16<<<ggrd, 256, 0, stream>>>(x1f, Wt2, dinv, gbuf);
    k_agg_s<<<8 * (MP / 32), 256, 0, stream>>>(gbuf, dinv, offs, csr, sorted, b2, x2h);

    // --- global max pool (out zeroed by memset)
    k_maxpool<<<MAXP_BLOCKS, 256, 0, stream>>>(x2h, out);
}